// Round 9
// baseline (222.277 us; speedup 1.0000x reference)
//
#include <hip/hip_runtime.h>
#include <stdint.h>

// LinearAttention MI355X round 13: homogeneous per-head k_fused blocks.
// Grid (32,8,8): block (m0,h,b) computes the 192-col composite tile
// {q h*64.., k h*64.., v h*64..} (W rows h*64 + {0,512,1024}); acc[2][3],
// 24 MFMA/K-step/wave (was 16), A staged 8x not 12x, all blocks identical.
// Epilogue formulas verbatim round-11 (col-tile ct: 0,1=q 2,3=k 4,5=v).
// k_oy / k_kvred / k_tx / k_convW verbatim round 12.
// B=8, DIM=256, HEADS=8, DHEAD=64, HID=512, NPIX=4096.

#define NPIX 4096
#define HIDC 512
#define DIMC 256
#define BATCH 8

typedef __attribute__((ext_vector_type(8))) short bf16x8;
typedef __attribute__((ext_vector_type(4))) float f32x4;
typedef __attribute__((ext_vector_type(16))) float f32x16;

__device__ __forceinline__ float bf2f(unsigned short h) {
    unsigned int u = ((unsigned int)h) << 16; float f;
    __builtin_memcpy(&f, &u, 4); return f;
}
__device__ __forceinline__ unsigned short f2bf(float f) {
    unsigned int u; __builtin_memcpy(&u, &f, 4);
    u += 0x7fffu + ((u >> 16) & 1u);
    return (unsigned short)(u >> 16);
}
__device__ __forceinline__ float elu1(float x) {
    return x > 0.f ? x + 1.f : __expf(x);
}
// async global->LDS, 16B per lane. LDS dest = wave-uniform base + lane*16.
__device__ __forceinline__ void gl16(const unsigned short* g, unsigned short* l) {
    __builtin_amdgcn_global_load_lds(
        (__attribute__((address_space(1))) const void*)g,
        (__attribute__((address_space(3))) void*)l, 16, 0, 0);
}

// ---------------- K0a: weight conversion ----------------
// Wqkv -> Wb linear bf16. Wout -> Wpo packed fragment order (R8 formula).
__global__ __launch_bounds__(256) void k_convW(
    const float* __restrict__ Wqkv, const float* __restrict__ Wout,
    unsigned short* __restrict__ Wb, unsigned short* __restrict__ Wpo)
{
    int i4 = (blockIdx.x * 256 + threadIdx.x) * 4;
    const int NW1 = 1536 * 256;
    if (i4 < NW1) {
        float4 v = *(const float4*)&Wqkv[i4];
        ushort4 u; u.x = f2bf(v.x); u.y = f2bf(v.y); u.z = f2bf(v.z); u.w = f2bf(v.w);
        *(ushort4*)&Wb[i4] = u;
    } else {
        int jj = i4 - NW1;
        float4 v = *(const float4*)&Wout[jj];
        ushort4 u; u.x = f2bf(v.x); u.y = f2bf(v.y); u.z = f2bf(v.z); u.w = f2bf(v.w);
        const int o = jj >> 9, c = jj & 511;
        const int og = o >> 5, l31 = o & 31;
        const int ks = c >> 4, lhi = (c >> 3) & 1, j = c & 7;
        *(ushort4*)&Wpo[og * 16384 + ks * 512 + (l31 * 2 + lhi) * 8 + j] = u;
    }
}

// ---------------- K0b: x transpose+convert ----------------
__global__ __launch_bounds__(256) void k_tx(
    const float* __restrict__ x, unsigned short* __restrict__ xT)
{
    __shared__ float tile[32][33];
    const int n0 = blockIdx.x * 32, c0 = blockIdx.y * 32, b = blockIdx.z;
    const int t = threadIdx.x;
    const int r = t >> 3, c4 = (t & 7) * 4;
    float4 v = *(const float4*)&x[((size_t)b * DIMC + c0 + r) * NPIX + n0 + c4];
    tile[r][c4 + 0] = v.x; tile[r][c4 + 1] = v.y;
    tile[r][c4 + 2] = v.z; tile[r][c4 + 3] = v.w;
    __syncthreads();
    ushort4 o;
    unsigned short* op = (unsigned short*)&o;
#pragma unroll
    for (int i = 0; i < 4; i++) op[i] = f2bf(tile[c4 + i][r]);
    *(ushort4*)&xT[((size_t)b * NPIX + n0 + r) * DIMC + c0 + c4] = o;
}

// ---------------- K1: fused qkv GEMM + kv/ksum epilogue (per-head blocks) ----
// grid (32 px-tiles, 8 heads, 8 b) = 2048 blocks, 256 thr (4 waves, 2wm x 2wn).
// Per block: 128 px x 192 cols (64 q | 64 k | 64 v of head h), K=256, BK=64.
// Staging swizzle verbatim: LDS 16B chunk c of row r holds global chunk
// c ^ (r&7). Bounce kvS[128][128] verbatim round-11.
__global__ __launch_bounds__(256) void k_fused(
    const unsigned short* __restrict__ xT,   // B x 4096 x 256
    const unsigned short* __restrict__ Wb,   // 1536 x 256
    const float* __restrict__ cmp,           // B x 4096
    const float* __restrict__ csp,
    unsigned short* __restrict__ qT,         // B x 4096 x 512 (pixel-major)
    float* __restrict__ kvq,                 // (B*8) x 32 x 64 x 64 partials
    float* __restrict__ ksump)               // (B*8) x 64
{
    const int b  = blockIdx.z;
    const int h  = blockIdx.y;
    const int m0 = blockIdx.x * 128;
    const int t = threadIdx.x;
    const int wave = t >> 6, lane = t & 63;
    const int wm = wave >> 1, wn = wave & 1;
    const int l31 = lane & 31, lhi = lane >> 5;

    __shared__ unsigned short sh[320 * 64];         // 40 KB
    unsigned short* As  = sh;                       // [128 px][64 k]
    unsigned short* Bs  = sh + 128 * 64;            // [192 col][64 k]
    unsigned short* kvS = sh;                       // epilogue reuse [128][128]

    const unsigned short* Ag = xT + ((size_t)b * NPIX + m0) * DIMC;

    f32x16 acc[2][3];
#pragma unroll
    for (int i = 0; i < 2; i++)
#pragma unroll
        for (int j = 0; j < 3; j++)
#pragma unroll
            for (int r = 0; r < 16; r++) acc[i][j][r] = 0.f;

    const int r8  = lane >> 3;
    const int jg8 = (((lane & 7) ^ r8) & 7) * 8;     // swizzled global chunk
    const int xsw = (l31 & 7);

    for (int k0 = 0; k0 < DIMC; k0 += 64) {
        // A: 128 rows, 32/wave (4 x gl16 of 8 rows)
#pragma unroll
        for (int i = 0; i < 4; i++) {
            const int rowg = wave * 32 + i * 8;
            gl16(&Ag[(size_t)(rowg + r8) * DIMC + k0 + jg8], &As[rowg * 64]);
        }
        // B: 192 composite rows, 48/wave (6 x gl16 of 8 rows)
#pragma unroll
        for (int i = 0; i < 6; i++) {
            const int rowb = wave * 48 + i * 8;
            const int arow = rowb + r8;
            const int wrow = (arow < 64)  ? (h * 64 + arow)
                           : (arow < 128) ? (512 + h * 64 + (arow - 64))
                                          : (1024 + h * 64 + (arow - 128));
            gl16(&Wb[(size_t)wrow * DIMC + k0 + jg8], &Bs[rowb * 64]);
        }
        __syncthreads();
#pragma unroll
        for (int ks = 0; ks < 4; ks++) {
            const int coff = ((ks * 2 + lhi) ^ xsw) * 8;
            bf16x8 af[2], bfg[3];
#pragma unroll
            for (int fm = 0; fm < 2; fm++)
                af[fm] = *(const bf16x8*)&As[(wm * 64 + fm * 32 + l31) * 64 + coff];
#pragma unroll
            for (int fn = 0; fn < 3; fn++)
                bfg[fn] = *(const bf16x8*)&Bs[(wn * 96 + fn * 32 + l31) * 64 + coff];
#pragma unroll
            for (int fm = 0; fm < 2; fm++)
#pragma unroll
                for (int fn = 0; fn < 3; fn++)
                    acc[fm][fn] = __builtin_amdgcn_mfma_f32_32x32x16_bf16(
                        af[fm], bfg[fn], acc[fm][fn], 0, 0, 0);
        }
        __syncthreads();
    }

    // ---- epilogue: ct = wn*3+fn; 0,1 = q-write, 2,3 = k, 4,5 = v ----
    const float cs = *csp;
    float gv4[2];
#pragma unroll
    for (int fm = 0; fm < 2; fm++)
        gv4[fm] = 1.f + cs * cmp[(size_t)b * NPIX + m0 + wm * 64 + fm * 32 + l31];

    float gk[2][16];
#pragma unroll
    for (int fm = 0; fm < 2; fm++)
#pragma unroll
        for (int r = 0; r < 16; r++)
            gk[fm][r] = __shfl(gv4[fm], (r & 3) + 8 * (r >> 2) + 4 * lhi);

    float ksl = 0.f;
#pragma unroll
    for (int fn = 0; fn < 3; fn++) {
        const int ct = wn * 3 + fn;
        if (ct <= 1) {
            // q-write: global col = h*64 + ct*32 + l31
            const int o = h * 64 + ct * 32 + l31;
#pragma unroll
            for (int fm = 0; fm < 2; fm++) {
                const int pbase = m0 + wm * 64 + fm * 32;
#pragma unroll
                for (int r = 0; r < 16; r++) {
                    int prow = pbase + (r & 3) + 8 * (r >> 2) + 4 * lhi;
                    qT[((size_t)b * NPIX + prow) * HIDC + o] = f2bf(elu1(acc[fm][fn][r]));
                }
            }
        } else {
            const int o = (ct - 2) * 32 + l31;       // bounce row: 0..63 k, 64..127 v
            const bool isK = (ct <= 3);
            const int sw = (o & 7) << 3;
#pragma unroll
            for (int fm = 0; fm < 2; fm++) {
#pragma unroll
                for (int rg = 0; rg < 4; rg++) {
                    ushort4 pk4;
                    unsigned short* pp = (unsigned short*)&pk4;
#pragma unroll
                    for (int j = 0; j < 4; j++) {
                        const int r = rg * 4 + j;
                        float val = acc[fm][fn][r];
                        if (isK) {
                            float kvl = elu1(val) * gk[fm][r];
                            ksl += kvl;
                            pp[j] = f2bf(kvl);
                        } else {
                            pp[j] = f2bf(val);
                        }
                    }
                    const int px0 = wm * 64 + fm * 32 + rg * 8 + 4 * lhi;
                    *(ushort4*)&kvS[(size_t)o * 128 + (px0 ^ sw)] = pk4;
                }
            }
        }
    }
    // ksum: wn0 handled ct2 (k-ch l31), wn1 handled ct3 (k-ch 32+l31)
    atomicAdd(&ksump[(size_t)(b * 8 + h) * 64 + wn * 32 + l31], ksl);
    __syncthreads();   // kvS fully written

    // kv partial: 64x64 over K=128 pixels; 4 waves, 32x32 quadrants (verbatim)
    f32x16 kva;
#pragma unroll
    for (int r = 0; r < 16; r++) kva[r] = 0.f;
#pragma unroll
    for (int pk = 0; pk < 8; pk++) {
        const int co = ((pk * 2 + lhi) ^ (l31 & 7)) * 8;
        bf16x8 kf = *(const bf16x8*)&kvS[(size_t)(wm * 32 + l31) * 128 + co];
        bf16x8 vf = *(const bf16x8*)&kvS[(size_t)(64 + wn * 32 + l31) * 128 + co];
        kva = __builtin_amdgcn_mfma_f32_32x32x16_bf16(kf, vf, kva, 0, 0, 0);
    }
    float* kvb = kvq + ((size_t)(b * 8 + h) * 32 + blockIdx.x) * 4096;
#pragma unroll
    for (int r = 0; r < 16; r++) {
        const int d = wm * 32 + (r & 3) + 8 * (r >> 2) + 4 * lhi;
        kvb[(size_t)d * 64 + wn * 32 + l31] = kva[r];
    }
}

// ---------------- K2: kv partial reduce (32 slots -> kvp) ----------------
__global__ __launch_bounds__(256) void k_kvred(
    const float* __restrict__ kvq, float* __restrict__ kvp)
{
    const int bh = blockIdx.x >> 2, q4 = blockIdx.x & 3;
    const float4* src = (const float4*)(kvq + (size_t)bh * 32 * 4096)
                      + q4 * 256 + threadIdx.x;
    float4 s; s.x = 0.f; s.y = 0.f; s.z = 0.f; s.w = 0.f;
#pragma unroll 8
    for (int i = 0; i < 32; i++) {
        float4 v = src[(size_t)i * 1024];
        s.x += v.x; s.y += v.y; s.z += v.z; s.w += v.w;
    }
    ((float4*)(kvp + (size_t)bh * 4096))[q4 * 256 + threadIdx.x] = s;
}

// ---------------- K3: fused out+y: y = Wout·(z·kv^T q) + bout ----------------
// (verbatim round 12)
__global__ __launch_bounds__(256, 2) void k_oy(
    const unsigned short* __restrict__ qT,   // B x 4096 x 512
    const float* __restrict__ kvp,           // (B*8) x 64 x 64  (d-major)
    const float* __restrict__ ksum,          // (B*8) x 64
    const unsigned short* __restrict__ Wpo,  // packed 256 x 512
    const float* __restrict__ bout,
    float* __restrict__ y)                   // B x 256 x 4096
{
    const int b  = blockIdx.y;
    const int px0 = blockIdx.x * 64;
    const int t = threadIdx.x;
    const int wave = t >> 6, lane = t & 63;
    const int pxh = wave & 1, whi = wave >> 1;   // whi: eh (out) / oh (y)
    const int l31 = lane & 31, lhi = lane >> 5;
    const int lidx = (l31 * 2 + lhi) * 8;

    __shared__ unsigned short qS[2][64 * 64];   // 16 KB q dbuf (XOR-swz)
    __shared__ unsigned short kvS2[64 * 72];    // 9 KB kvT [e][d] pad-72
    __shared__ unsigned short outS[64 * 64];    // 8 KB out [px][e] XOR-swz
    __shared__ float ksS[64];

    const int r8 = lane >> 3;
    const int jg8 = ((lane & 7) ^ r8) * 8;

    auto stageQ = [&](int h, int buf) {
        const unsigned short* qg = qT + ((size_t)b * NPIX + px0) * HIDC + h * 64;
#pragma unroll
        for (int i = 0; i < 2; i++) {
            const int rowb = wave * 16 + i * 8;
            gl16(&qg[(size_t)(rowb + r8) * HIDC + jg8], &qS[buf][rowb * 64]);
        }
    };
    auto stageKV = [&](int h) {
        const float* kvg = kvp + (size_t)(b * 8 + h) * 4096;
#pragma unroll
        for (int i = 0; i < 16; i++) {
            int idx = t + i * 256;
            int d = idx >> 6, e = idx & 63;
            kvS2[e * 72 + d] = f2bf(kvg[idx]);
        }
        if (t < 64) ksS[t] = ksum[(size_t)(b * 8 + h) * 64 + t];
    };

    stageQ(0, 0);
    stageKV(0);

    f32x16 yacc[4];
#pragma unroll
    for (int mt = 0; mt < 4; mt++)
#pragma unroll
        for (int r = 0; r < 16; r++) yacc[mt][r] = 0.f;

    int cur = 0;
    __syncthreads();

#pragma unroll 1
    for (int h = 0; h < 8; h++) {
        bf16x8 qf[4];
#pragma unroll
        for (int s = 0; s < 4; s++)
            qf[s] = *(const bf16x8*)&qS[cur][(pxh * 32 + l31) * 64
                                            + (((s * 2 + lhi) ^ (l31 & 7)) * 8)];
        f32x16 oacc;
#pragma unroll
        for (int r = 0; r < 16; r++) oacc[r] = 0.f;
#pragma unroll
        for (int s = 0; s < 4; s++) {
            bf16x8 kvf = *(const bf16x8*)&kvS2[(whi * 32 + l31) * 72 + s * 16 + lhi * 8];
            oacc = __builtin_amdgcn_mfma_f32_32x32x16_bf16(kvf, qf[s], oacc, 0, 0, 0);
        }
        float den = 0.f;
#pragma unroll
        for (int s = 0; s < 4; s++) {
            f32x4 ka = *(const f32x4*)&ksS[s * 16 + lhi * 8];
            f32x4 kb = *(const f32x4*)&ksS[s * 16 + lhi * 8 + 4];
            const unsigned short* qp = (const unsigned short*)&qf[s];
#pragma unroll
            for (int j = 0; j < 4; j++) {
                den += bf2f(qp[j]) * ka[j];
                den += bf2f(qp[4 + j]) * kb[j];
            }
        }
        den += __shfl_xor(den, 32);
        const float z = 1.f / (den + 1e-6f);

        ushort4 op4[4];
#pragma unroll
        for (int rg = 0; rg < 4; rg++) {
            unsigned short* pp = (unsigned short*)&op4[rg];
#pragma unroll
            for (int j = 0; j < 4; j++)
                pp[j] = f2bf(oacc[rg * 4 + j] * z);
        }

        __syncthreads();   // A: all waves done reading outS (prev) & kvS2/ksS
        {
            const int px = pxh * 32 + l31;
#pragma unroll
            for (int rg = 0; rg < 4; rg++)
                *(ushort4*)&outS[px * 64 + (((whi * 4 + rg) ^ (px & 7)) * 8) + 4 * lhi]
                    = op4[rg];
        }
        if (h < 7) { stageQ(h + 1, cur ^ 1); stageKV(h + 1); }
        __syncthreads();   // B: outS + next kv staged

#pragma unroll
        for (int k16 = 0; k16 < 4; k16++) {
            const int px = pxh * 32 + l31;
            bf16x8 of = *(const bf16x8*)&outS[px * 64 + (((k16 * 2 + lhi) ^ (px & 7)) * 8)];
#pragma unroll
            for (int mt = 0; mt < 4; mt++) {
                bf16x8 wf = *(const bf16x8*)&Wpo[(size_t)(whi * 4 + mt) * 16384
                                                 + (h * 4 + k16) * 512 + lidx];
                yacc[mt] = __builtin_amdgcn_mfma_f32_32x32x16_bf16(wf, of, yacc[mt], 0, 0, 0);
            }
        }
        cur ^= 1;
    }

#pragma unroll
    for (int mt = 0; mt < 4; mt++) {
#pragma unroll
        for (int r = 0; r < 16; r++) {
            const int o = whi * 128 + mt * 32 + (r & 3) + 8 * (r >> 2) + 4 * lhi;
            y[((size_t)b * DIMC + o) * NPIX + px0 + pxh * 32 + l31]
                = yacc[mt][r] + bout[o];
        }
    }
}

extern "C" void kernel_launch(void* const* d_in, const int* in_sizes, int n_in,
                              void* d_out, int out_size, void* d_ws, size_t ws_size,
                              hipStream_t stream) {
    (void)in_sizes; (void)n_in; (void)out_size; (void)ws_size;
    const float* x    = (const float*)d_in[0];
    const float* cm   = (const float*)d_in[1];
    const float* Wqkv = (const float*)d_in[2];
    const float* Wout = (const float*)d_in[3];
    const float* bout = (const float*)d_in[4];
    const float* csp  = (const float*)d_in[5];
    float* y = (float*)d_out;

    const size_t qn = (size_t)BATCH * HIDC * NPIX;
    char* ws = (char*)d_ws;
    unsigned short* qT   = (unsigned short*)ws;                 ws += qn * 2;
    unsigned short* xT   = (unsigned short*)ws;                 ws += qn * 2;
    float* kvp   = (float*)ws;                                  ws += (size_t)64 * 64 * 64 * 4;
    float* ksump = (float*)ws;                                  ws += (size_t)64 * 64 * 4;
    float* kvq   = (float*)ws;                                  ws += (size_t)64 * 32 * 4096 * 4;
    unsigned short* Wb  = (unsigned short*)ws;                  ws += (size_t)1536 * 256 * 2;
    unsigned short* Wpo = (unsigned short*)ws;

    hipMemsetAsync(ksump, 0, (size_t)64 * 64 * sizeof(float), stream);
    k_convW<<<512, 256, 0, stream>>>(Wqkv, Wout, Wb, Wpo);
    k_tx   <<<dim3(128, 8, 8), 256, 0, stream>>>(x, xT);
    k_fused<<<dim3(32, 8, 8),  256, 0, stream>>>(xT, Wb, cm, csp, qT, kvq, ksump);
    k_kvred<<<256, 256, 0, stream>>>(kvq, kvp);
    k_oy   <<<dim3(64, 8),     256, 0, stream>>>(qT, kvp, ksump, Wpo, bout, y);
}